// Round 6
// baseline (523.661 us; speedup 1.0000x reference)
//
#include <hip/hip_runtime.h>
#include <hip/hip_bf16.h>
#include <cstdint>

#define S_LEN 2304
#define NDIM  3072
#define NH    24
#define HD    128

typedef unsigned short u16;
typedef __bf16  bf16x8  __attribute__((ext_vector_type(8)));
typedef float   floatx4 __attribute__((ext_vector_type(4)));

// HW bf16 convert (RNE) -- compiler pairs into v_cvt_pk_bf16_f32.
__device__ __forceinline__ u16 f2bf(float x) {
  union { __bf16 b; u16 u; } c;
  c.b = (__bf16)x;
  return c.u;
}

// async 16B global->LDS (direct-to-shared DMA). LDS dest must be
// wave-uniform base + lane*16 -- all call sites arrange that.
__device__ __forceinline__ void async_load16(const void* g, void* l) {
  auto gp = (const __attribute__((address_space(1))) unsigned int*)(unsigned long long)(g);
  auto lp = (__attribute__((address_space(3))) unsigned int*)(unsigned int)(unsigned long long)(l);
  __builtin_amdgcn_global_load_lds(gp, lp, 16, 0, 0);
}

// ------------------------------------------- fp32->bf16, all 5 tensors fused
// Lane-unit-stride: per wave both loads are contiguous 1KB bursts.
__global__ __launch_bounds__(256) void cvt_all(const float* __restrict__ x,
                                               const float* __restrict__ w0,
                                               const float* __restrict__ w1,
                                               const float* __restrict__ w2,
                                               const float* __restrict__ w3,
                                               u16* __restrict__ xo,
                                               u16* __restrict__ o0,
                                               u16* __restrict__ o1,
                                               u16* __restrict__ o2,
                                               u16* __restrict__ o3) {
  long b = blockIdx.x;
  const float* in; u16* out;
  if (b < 3456) { in = x; out = xo; }
  else {
    long wi = (b - 3456) / 4608;
    b = (b - 3456) % 4608;
    in  = (wi == 0) ? w0 : (wi == 1) ? w1 : (wi == 2) ? w2 : w3;
    out = (wi == 0) ? o0 : (wi == 1) ? o1 : (wi == 2) ? o2 : o3;
  }
  const long f4 = b * 512 + threadIdx.x;      // float4 index
  const float4* in4 = (const float4*)in;
  float4 a = in4[f4];
  float4 c = in4[f4 + 256];
  union { u16 h[4]; uint2 u; } r0, r1;
  r0.h[0] = f2bf(a.x); r0.h[1] = f2bf(a.y); r0.h[2] = f2bf(a.z); r0.h[3] = f2bf(a.w);
  r1.h[0] = f2bf(c.x); r1.h[1] = f2bf(c.y); r1.h[2] = f2bf(c.z); r1.h[3] = f2bf(c.w);
  *(uint2*)(out + f4 * 4)         = r0.u;
  *(uint2*)(out + (f4 + 256) * 4) = r1.u;
}

// ---------------------------------------------------------------- GEMM core
// C[M,N] = A[M,K] @ B[N,K]^T.  A,B bf16; acc fp32.
// PROVEN structure (887 TF / 145us qkv measured on this problem): 128x128
// tile, BK=64, 256 threads = 4 waves of 64x64, single-buffered LDS (32 KB ->
// ~2 blocks/CU; cross-block wave overlap hides the barrier drain).
// Grid mapping: PLAIN x-fastest over N-tiles (measured optimum; both XCD
// swizzle variants regressed: round-robin 161MB fetch vs chunked 503MB).
__device__ __forceinline__ void gemm_core128(const u16* __restrict__ A,
                                             const u16* __restrict__ B,
                                             int bm, int bn,
                                             u16* As, u16* Bs,
                                             floatx4 acc[4][4]) {
  constexpr int K = NDIM;
  const int t = threadIdx.x;
  const int l = t & 63, w = t >> 6;
  const int l15 = l & 15, quad = l >> 4;
  const int wm = (w >> 1) * 64, wn = (w & 1) * 64;

#pragma unroll
  for (int i = 0; i < 4; ++i)
#pragma unroll
    for (int j = 0; j < 4; ++j) acc[i][j] = {0.f, 0.f, 0.f, 0.f};

  for (int kt = 0; kt < K / 64; ++kt) {
    const int k0 = kt * 64;
#pragma unroll
    for (int i = 0; i < 4; ++i) {
      int p = i * 256 + t;            // chunk index 0..1023 (wave-contiguous)
      int r = p >> 3;
      int c = (p & 7) ^ (r & 7);      // fetch the chunk that lands swizzled
      async_load16(A + (long)(bm + r) * K + k0 + c * 8, As + p * 8);
      async_load16(B + (long)(bn + r) * K + k0 + c * 8, Bs + p * 8);
    }
    __syncthreads();
#pragma unroll
    for (int kk = 0; kk < 2; ++kk) {
      bf16x8 af[4], bfr[4];
#pragma unroll
      for (int i = 0; i < 4; ++i) {
        int row = wm + i * 16 + l15;
        int cc = kk * 4 + quad;
        af[i] = *(const bf16x8*)(As + (row * 8 + (cc ^ (row & 7))) * 8);
      }
#pragma unroll
      for (int j = 0; j < 4; ++j) {
        int row = wn + j * 16 + l15;
        int cc = kk * 4 + quad;
        bfr[j] = *(const bf16x8*)(Bs + (row * 8 + (cc ^ (row & 7))) * 8);
      }
#pragma unroll
      for (int i = 0; i < 4; ++i)
#pragma unroll
        for (int j = 0; j < 4; ++j)
          acc[i][j] = __builtin_amdgcn_mfma_f32_16x16x32_bf16(af[i], bfr[j], acc[i][j], 0, 0, 0);
    }
    __syncthreads();
  }
}

// fused Q,K,V projection: grid dim3(72, 18), x = (sel, N-tile), y = M-tile.
// q,k -> fp32 (RMSNorm wants fp32); v -> bf16 written DIRECTLY TRANSPOSED
// into the attn V^T layout [3072][S] (per lane the 4 acc rows are contiguous
// M -> one 8B store; bit-identical to a separate transpose pass).
__global__ __launch_bounds__(256, 2) void gemm_qkv(const u16* __restrict__ A,
                                                   const u16* __restrict__ wq,
                                                   const u16* __restrict__ wk,
                                                   const u16* __restrict__ wv,
                                                   const float* __restrict__ bq,
                                                   const float* __restrict__ bk,
                                                   const float* __restrict__ bv,
                                                   float* __restrict__ qf,
                                                   float* __restrict__ kf,
                                                   u16* __restrict__ vt) {
  __shared__ u16 As[128 * 64];
  __shared__ u16 Bs[128 * 64];
  const int sel = blockIdx.x / 24;            // 0:q 1:k 2:v
  const int bn = (blockIdx.x % 24) * 128;
  const int bm = blockIdx.y * 128;
  const u16* Bw = (sel == 0) ? wq : (sel == 1) ? wk : wv;
  const float* bias = (sel == 0) ? bq : (sel == 1) ? bk : bv;

  floatx4 acc[4][4];
  gemm_core128(A, Bw, bm, bn, As, Bs, acc);

  const int t = threadIdx.x;
  const int l = t & 63, w = t >> 6;
  const int l15 = l & 15, quad = l >> 4;
  const int wm = (w >> 1) * 64, wn = (w & 1) * 64;

  if (sel < 2) {
    float* C = sel ? kf : qf;
#pragma unroll
    for (int i = 0; i < 4; ++i) {
      const int gm = bm + wm + i * 16 + quad * 4;
#pragma unroll
      for (int j = 0; j < 4; ++j) {
        const int gn = bn + wn + j * 16 + l15;
        const float bb = bias[gn];
#pragma unroll
        for (int r = 0; r < 4; ++r)
          C[(long)(gm + r) * NDIM + gn] = acc[i][j][r] + bb;
      }
    }
  } else {
#pragma unroll
    for (int i = 0; i < 4; ++i) {
      const int gm = bm + wm + i * 16 + quad * 4;   // token index, 4-aligned
#pragma unroll
      for (int j = 0; j < 4; ++j) {
        const int gn = bn + wn + j * 16 + l15;      // v-channel = h*128+d
        const float bb = bias[gn];
        union { u16 h[4]; uint2 u; } o;
#pragma unroll
        for (int r = 0; r < 4; ++r) o.h[r] = f2bf(acc[i][j][r] + bb);
        *(uint2*)(vt + (long)gn * S_LEN + gm) = o.u;
      }
    }
  }
}

// output projection: grid dim3(24, 18), x = N-tile, y = M-tile.
__global__ __launch_bounds__(256, 2) void gemm_bt(const u16* __restrict__ A,
                                                  const u16* __restrict__ Bw,
                                                  const float* __restrict__ bias,
                                                  float* __restrict__ C) {
  __shared__ u16 As[128 * 64];
  __shared__ u16 Bs[128 * 64];
  const int bm = blockIdx.y * 128;
  const int bn = blockIdx.x * 128;

  floatx4 acc[4][4];
  gemm_core128(A, Bw, bm, bn, As, Bs, acc);

  const int t = threadIdx.x;
  const int l = t & 63, w = t >> 6;
  const int l15 = l & 15, quad = l >> 4;
  const int wm = (w >> 1) * 64, wn = (w & 1) * 64;
#pragma unroll
  for (int i = 0; i < 4; ++i) {
    const int gm = bm + wm + i * 16 + quad * 4;
#pragma unroll
    for (int j = 0; j < 4; ++j) {
      const int gn = bn + wn + j * 16 + l15;
      const float bb = bias[gn];
#pragma unroll
      for (int r = 0; r < 4; ++r)
        C[(long)(gm + r) * NDIM + gn] = acc[i][j][r] + bb;
    }
  }
}

// --------------------------------------------------- fused RMSNorm + 3D RoPE
// blockIdx.y: 0 -> q, 1 -> k
__global__ __launch_bounds__(256) void rmsnorm_rope(const float* __restrict__ qxf,
                                                    const float* __restrict__ kxf,
                                                    const float* __restrict__ gqp,
                                                    const float* __restrict__ gkp,
                                                    const float* __restrict__ freqs,
                                                    const int* __restrict__ gsz,
                                                    u16* __restrict__ qop,
                                                    u16* __restrict__ kop) {
  const int tok = blockIdx.x;
  const int tid = threadIdx.x;
  const float* xf = blockIdx.y ? kxf : qxf;
  const float* g  = blockIdx.y ? gkp : gqp;
  u16* outp       = blockIdx.y ? kop : qop;
  const float* row = xf + (long)tok * NDIM;
  float4 v[3];
  float ss = 0.f;
#pragma unroll
  for (int p = 0; p < 3; ++p) {
    v[p] = ((const float4*)row)[p * 256 + tid];
    ss += v[p].x * v[p].x + v[p].y * v[p].y + v[p].z * v[p].z + v[p].w * v[p].w;
  }
#pragma unroll
  for (int m = 1; m < 64; m <<= 1) ss += __shfl_xor(ss, m);
  __shared__ float red[4];
  if ((tid & 63) == 0) red[tid >> 6] = ss;
  __syncthreads();
  ss = red[0] + red[1] + red[2] + red[3];
  const float scale = rsqrtf(ss * (1.0f / NDIM) + 1e-6f);

  const int gh = gsz[1], gw = gsz[2];
  const int hw = gh * gw;
  const int fi = tok / hw;
  const int hi = (tok % hw) / gw;
  const int wi = tok % gw;
#pragma unroll
  for (int p = 0; p < 3; ++p) {
    const int e0 = (p * 256 + tid) * 4;
    const float4 gg = ((const float4*)g)[p * 256 + tid];
    const int hh = e0 >> 7;
    const int d = e0 & 127;
    const int c0 = d >> 1;
    int pos0 = (c0 < 22) ? fi : ((c0 < 43) ? hi : wi);
    int pos1 = (c0 + 1 < 22) ? fi : ((c0 + 1 < 43) ? hi : wi);
    float th0 = freqs[pos0 * 64 + c0];
    float th1 = freqs[pos1 * 64 + c0 + 1];
    float s0, cc0, s1, cc1;
    __sincosf(th0, &s0, &cc0);
    __sincosf(th1, &s1, &cc1);
    float x0 = v[p].x * scale * gg.x;
    float x1 = v[p].y * scale * gg.y;
    float x2 = v[p].z * scale * gg.z;
    float x3 = v[p].w * scale * gg.w;
    union { u16 h[4]; uint2 u; } o;
    o.h[0] = f2bf(x0 * cc0 - x1 * s0);
    o.h[1] = f2bf(x0 * s0 + x1 * cc0);
    o.h[2] = f2bf(x2 * cc1 - x3 * s1);
    o.h[3] = f2bf(x2 * s1 + x3 * cc1);
    *(uint2*)(outp + ((long)hh * S_LEN + tok) * HD + d) = o.u;
  }
}

// ------------------------------------------------------------ flash attention
// qb,kb: bf16 [NH][S][HD]; vt: bf16 [NH*HD][S]; out: bf16 [S][3072].
// 216 blocks x 512 threads (8 waves x 32 q-rows -> Q-tile 256). K-tile = 64.
// SWAPPED-OPERAND form: sacc = mfma(K,Q) puts P^T in registers (col=q=l15,
// rows=4 k-tokens). PV consumes P as the B operand with a k-slot remap
// token = f*32+(j>>2)*16+quad*4+(j&3) applied identically to the V A-frag
// (LDS read) -> P never touches LDS (the old 32 ds_write_b16 + reread per
// tile is gone, Ps buffer freed: LDS 96->64 KB). Output lands transposed
// (col=q, 4 consecutive d per lane) -> contiguous 8B stores.
// NO online max (post-RMSNorm scores fp32-safe unshifted); row-sum l via
// mfma(ones, P) -- all C rows equal, use reg 0.
__global__ __launch_bounds__(512, 2) void attn_kern(const u16* __restrict__ qb,
                                                    const u16* __restrict__ kb,
                                                    const u16* __restrict__ vt,
                                                    const int* __restrict__ seq_lens,
                                                    u16* __restrict__ ob) {
  __shared__ u16 Kb[2][64 * 128];   // K tile: 64 tok rows x 16 chunks, swz 15
  __shared__ u16 Vb[2][128 * 64];   // V^T tile: 128 d rows x 8 chunks, swz 7
  const int b = blockIdx.x;           // 0..215
  const int xcd = b & 7;
  const int slot = b >> 3;            // 0..26
  const int h = xcd * 3 + slot / 9;   // 3 heads per XCD
  const int qt = slot % 9;
  const int t = threadIdx.x;
  const int l = t & 63, w = t >> 6;   // 8 waves
  const int l15 = l & 15, quad = l >> 4;
  const int seqlen = seq_lens[0];
  const float SC2 = 0.12753102543f;   // (1/sqrt(128)) * log2(e), for exp2f

  const u16* kbase = kb + (long)h * S_LEN * HD;
  const u16* vbase = vt + (long)h * HD * S_LEN;

  // Q fragments (B-operand): n = lane&15, k = quad*8 + j (+ kk*32 over d)
  bf16x8 qfrag[2][4];
#pragma unroll
  for (int i = 0; i < 2; ++i) {
    const u16* qrow = qb + ((long)h * S_LEN + qt * 256 + w * 32 + i * 16 + l15) * HD + quad * 8;
#pragma unroll
    for (int kk = 0; kk < 4; ++kk) qfrag[i][kk] = *(const bf16x8*)(qrow + kk * 32);
  }

  bf16x8 ones;
#pragma unroll
  for (int i = 0; i < 8; ++i) ones[i] = (__bf16)1.0f;

  // V read offsets (u16 units within a row): slot j=0..3 -> src chunk16
  // c16 = f*4 + (quad>>1), 8B half = quad&1; j=4..7 -> c16+2. Swizzle ^ (d&7)
  // where d&7 == l15&7 (row = dblk*16 + l15).
  const int lb = l15 & 7;
  const int qh = quad >> 1;
  const int q1 = (quad & 1) * 4;
  int vofs[4];
#pragma unroll
  for (int c = 0; c < 4; ++c)
    vofs[c] = ((qh + c * 2) ^ lb) * 8 + q1;   // c = f*2 + (j>>2 half)

  floatx4 oacc[2][8];   // [q-half][d-block]: col=q=l15, rows=4 d
  floatx4 lacc[2];
#pragma unroll
  for (int i = 0; i < 2; ++i) {
#pragma unroll
    for (int j = 0; j < 8; ++j) oacc[i][j] = {0.f, 0.f, 0.f, 0.f};
    lacc[i] = {0.f, 0.f, 0.f, 0.f};
  }

  // stage K-tile (64x128) + V-tile (128x64) for tile `kt` into buffer `buf`
  auto stage = [&](int kt, int buf) {
#pragma unroll
    for (int i = 0; i < 2; ++i) {
      int p = i * 512 + t;              // 0..1023
      int rk = p >> 4;                  // K: token row 0..63
      int ck = (p & 15) ^ (rk & 15);
      async_load16(kbase + ((long)(kt * 64 + rk)) * HD + ck * 8, &Kb[buf][p * 8]);
      int dv = p >> 3;                  // V: hd row 0..127
      int cv = (p & 7) ^ (dv & 7);
      async_load16(vbase + (long)dv * S_LEN + kt * 64 + cv * 8, &Vb[buf][p * 8]);
    }
  };

  // one K-tile step; cur is a compile-time constant at each call site
  auto step = [&](int kt, int cur) {
    __syncthreads();                   // tile kt loads done; prev compute done
    if (kt + 1 < S_LEN / 64) stage(kt + 1, cur ^ 1);

    // S^T = K Q^T : sacc[i][ks] col=q (l15 of half i), rows=k tok ks*16+quad*4+r
    floatx4 sacc[2][4];
#pragma unroll
    for (int i = 0; i < 2; ++i)
#pragma unroll
      for (int j = 0; j < 4; ++j) sacc[i][j] = {0.f, 0.f, 0.f, 0.f};
    __builtin_amdgcn_s_setprio(1);
#pragma unroll
    for (int kk = 0; kk < 4; ++kk) {
#pragma unroll
      for (int ks = 0; ks < 4; ++ks) {
        int row = ks * 16 + l15;
        int cc = kk * 4 + quad;
        bf16x8 bk = *(const bf16x8*)(&Kb[cur][(row * 16 + (cc ^ (row & 15))) * 8]);
        sacc[0][ks] = __builtin_amdgcn_mfma_f32_16x16x32_bf16(bk, qfrag[0][kk], sacc[0][ks], 0, 0, 0);
        sacc[1][ks] = __builtin_amdgcn_mfma_f32_16x16x32_bf16(bk, qfrag[1][kk], sacc[1][ks], 0, 0, 0);
      }
    }
    __builtin_amdgcn_s_setprio(0);

    // unshifted softmax numerator: p = 2^(s*SC2)  (masked rows -> 0)
    const bool tail = (kt * 64 + 64 > seqlen);
#pragma unroll
    for (int i = 0; i < 2; ++i)
#pragma unroll
      for (int ks = 0; ks < 4; ++ks)
#pragma unroll
        for (int r = 0; r < 4; ++r) {
          float sv = sacc[i][ks][r] * SC2;
          if (tail) {
            int tok = kt * 64 + ks * 16 + quad * 4 + r;
            if (tok >= seqlen) sv = -1e30f;
          }
          sacc[i][ks][r] = exp2f(sv);
        }

    // P fragments in-register (B-operand, slot j -> sacc[f*2+(j>>2)][j&3])
    // O^T += V^T P ; l += ones @ P
    __builtin_amdgcn_s_setprio(1);
#pragma unroll
    for (int f = 0; f < 2; ++f) {
      bf16x8 pf[2];
#pragma unroll
      for (int i = 0; i < 2; ++i) {
#pragma unroll
        for (int j = 0; j < 4; ++j) pf[i][j] = (__bf16)sacc[i][f * 2][j];
#pragma unroll
        for (int j = 0; j < 4; ++j) pf[i][4 + j] = (__bf16)sacc[i][f * 2 + 1][j];
      }
      lacc[0] = __builtin_amdgcn_mfma_f32_16x16x32_bf16(ones, pf[0], lacc[0], 0, 0, 0);
      lacc[1] = __builtin_amdgcn_mfma_f32_16x16x32_bf16(ones, pf[1], lacc[1], 0, 0, 0);
#pragma unroll
      for (int dblk = 0; dblk < 8; ++dblk) {
        const int rowb = (dblk * 16 + l15) * 64;
        union { bf16x8 v; uint2 u2[2]; } vf;
        vf.u2[0] = *(const uint2*)(&Vb[cur][rowb + vofs[f * 2]]);
        vf.u2[1] = *(const uint2*)(&Vb[cur][rowb + vofs[f * 2 + 1]]);
        oacc[0][dblk] = __builtin_amdgcn_mfma_f32_16x16x32_bf16(vf.v, pf[0], oacc[0][dblk], 0, 0, 0);
        oacc[1][dblk] = __builtin_amdgcn_mfma_f32_16x16x32_bf16(vf.v, pf[1], oacc[1][dblk], 0, 0, 0);
      }
    }
    __builtin_amdgcn_s_setprio(0);
  };

  stage(0, 0);
  for (int kt = 0; kt < S_LEN / 64; kt += 2) {
    step(kt, 0);
    step(kt + 1, 1);
  }

  // epilogue: lane holds O[q = i*16+l15][d = dblk*16+quad*4+r] -> 8B stores
#pragma unroll
  for (int i = 0; i < 2; ++i) {
    const float inv = 1.0f / lacc[i][0];
    const long gt = qt * 256 + w * 32 + i * 16 + l15;
#pragma unroll
    for (int dblk = 0; dblk < 8; ++dblk) {
      union { u16 h[4]; uint2 u; } o;
#pragma unroll
      for (int r = 0; r < 4; ++r) o.h[r] = f2bf(oacc[i][dblk][r] * inv);
      *(uint2*)(ob + gt * NDIM + h * HD + dblk * 16 + quad * 4) = o.u;
    }
  }
}

// ----------------------------------------------------------------------------
extern "C" void kernel_launch(void* const* d_in, const int* in_sizes, int n_in,
                              void* d_out, int out_size, void* d_ws, size_t ws_size,
                              hipStream_t stream) {
  const float* x        = (const float*)d_in[0];
  const int*   seq_lens = (const int*)  d_in[1];
  const int*   gsz      = (const int*)  d_in[2];
  const float* freqs    = (const float*)d_in[3];
  const float* wq       = (const float*)d_in[4];
  const float* bq       = (const float*)d_in[5];
  const float* wk       = (const float*)d_in[6];
  const float* bk       = (const float*)d_in[7];
  const float* wv       = (const float*)d_in[8];
  const float* bv       = (const float*)d_in[9];
  const float* wo       = (const float*)d_in[10];
  const float* bo       = (const float*)d_in[11];
  const float* gq       = (const float*)d_in[12];
  const float* gk       = (const float*)d_in[13];
  float* out = (float*)d_out;

  char* ws = (char*)d_ws;
  const size_t SD2 = (size_t)S_LEN * NDIM * 2;   // bf16 [S,3072]
  const size_t W2  = (size_t)NDIM * NDIM * 2;    // bf16 [3072,3072]
  const size_t SD4 = (size_t)S_LEN * NDIM * 4;   // fp32 [S,3072]
  size_t off = 0;
  u16* xb    = (u16*)(ws + off); off += SD2;
  u16* wqb   = (u16*)(ws + off); off += W2;
  u16* wkb   = (u16*)(ws + off); off += W2;
  u16* wvb   = (u16*)(ws + off); off += W2;
  u16* wob   = (u16*)(ws + off); off += W2;
  float* qf  = (float*)(ws + off); off += SD4;
  float* kf  = (float*)(ws + off); off += SD4;
  u16* vtb   = (u16*)(ws + off); off += SD2;     // V^T bf16 [3072,S]
  u16* qbuf  = (u16*)(ws + off); off += SD2;
  u16* kbuf  = (u16*)(ws + off); off += SD2;
  u16* attnb = (u16*)(ws + off); off += SD2;

  cvt_all<<<3456 + 4 * 4608, 256, 0, stream>>>(x, wq, wk, wv, wo,
                                               xb, wqb, wkb, wvb, wob);

  gemm_qkv<<<dim3(72, 18), 256, 0, stream>>>(xb, wqb, wkb, wvb,
                                             bq, bk, bv, qf, kf, vtb);

  rmsnorm_rope<<<dim3(S_LEN, 2), 256, 0, stream>>>(qf, kf, gq, gk, freqs, gsz,
                                                   qbuf, kbuf);

  attn_kern<<<216, 512, 0, stream>>>(qbuf, kbuf, vtb, seq_lens, attnb);

  gemm_bt<<<dim3(24, 18), 256, 0, stream>>>(attnb, wob, bo, out);
}